// Round 10
// baseline (371.830 us; speedup 1.0000x reference)
//
#include <hip/hip_runtime.h>
#include <hip/hip_bf16.h>
#include <hip/hip_cooperative_groups.h>

namespace cg = cooperative_groups;

// SimpleGNN on MI355X — fp32 in/out, edge_index int32/int64 auto-detect.
// out[d] = di[d]*(S[d] @ M) + di[d]*cnt_col[d]*c + b2
//   M = W1^T W2^T [128x64], c = b1 @ W2^T [64]
//   S[d] = sum_{e: col_e=d} x[row_e],  di[d] = 1/deg_row[d] (0 if deg 0)
// R10: single cooperative kernel, grid.sync() between the 4 phases
// (R7-R9 showed work-level cuts are neutral: dispatch overhead dominates).
// Fallback to 4 dispatches if cooperative launch is rejected.

#define IN_CH   128
#define OUT_CH  64
#define NCHUNK  112
#define NRANGE  4
#define RBINS   12544   // ceil(50176/4) -> supports n_nodes <= 50176
#define MC_BLOCKS 33    // ceil((128*64+64)/256)
#define GRID    512     // 2 blocks/CU at 66.6 KB LDS
#define SMEM_FLOATS (IN_CH * OUT_CH + 64 * (IN_CH + 4))   // 16640 floats = 66560 B

typedef unsigned short u16;
typedef unsigned int u32;

static __device__ inline float bfu32_lo(u32 u) { return __uint_as_float(u << 16); }
static __device__ inline float bfu32_hi(u32 u) { return __uint_as_float(u & 0xffff0000u); }
static __device__ inline u16 f2bf(float f) {
    __hip_bfloat16 h = __float2bfloat16(f);
    return *reinterpret_cast<u16*>(&h);
}

// wave-parallel stride detect: int64 edge_index => odd int32 words all 0
static __device__ inline int detect_stride_wave(const int* __restrict__ ei) {
    int lane = threadIdx.x & 63;
    int idx = (lane < 32) ? (2 * lane + 1) : 1;
    int v = ei[idx];
    unsigned long long m = __ballot((v != 0) && (lane < 32));
    return (m == 0ull) ? 2 : 1;
}

// ---------------- phase A1: M = W1^T W2^T, c = b1 @ W2^T ----------------
static __device__ void ph_Mc(int b, int tid,
                             const float* __restrict__ W1, const float* __restrict__ b1,
                             const float* __restrict__ W2,
                             float* __restrict__ M, float* __restrict__ c) {
    int t = b * 256 + tid;
    if (t < IN_CH * OUT_CH) {
        int o = t & (OUT_CH - 1);
        int i = t >> 6;
        float acc = 0.f;
        for (int h = 0; h < 128; ++h)
            acc += W1[h * 128 + i] * W2[o * 128 + h];
        M[i * OUT_CH + o] = acc;
    } else if (t < IN_CH * OUT_CH + OUT_CH) {
        int o = t - IN_CH * OUT_CH;
        float acc = 0.f;
        for (int h = 0; h < 128; ++h)
            acc += b1[h] * W2[o * 128 + h];
        c[o] = acc;
    }
}

// ---------------- phase A2: hist (row lo16, col hi16) ----------------
static __device__ void ph_hist(int j, int tid, float* __restrict__ smem,
                               const int* __restrict__ ei,
                               u16* __restrict__ row_slab, u16* __restrict__ col_slab,
                               int n_edges, int n_nodes) {
    u32* bins = (u32*)smem;
    int chunk = j % NCHUNK;
    int range = j / NCHUNK;
    int range_size = (n_nodes + NRANGE - 1) / NRANGE;
    int lo = range * range_size;
    int hi = lo + range_size; if (hi > n_nodes) hi = n_nodes;
    int nbins = hi - lo;
    if (nbins <= 0) return;

    int stride = detect_stride_wave(ei);
    for (int i = tid; i < nbins; i += 256) bins[i] = 0u;
    __syncthreads();

    size_t e0 = (size_t)chunk * n_edges / NCHUNK;
    size_t e1 = (size_t)(chunk + 1) * n_edges / NCHUNK;
    size_t cnt = e1 - e0;
    const int* rp = ei;
    const int* cp = ei + (size_t)n_edges * stride;

    size_t i = tid;
    int s[8], d[8];
    for (; i + 1792 < cnt; i += 2048) {
#pragma unroll
        for (int k = 0; k < 8; ++k) s[k] = rp[(e0 + i + 256 * k) * stride];
#pragma unroll
        for (int k = 0; k < 8; ++k) d[k] = cp[(e0 + i + 256 * k) * stride];
#pragma unroll
        for (int k = 0; k < 8; ++k) {
            if (s[k] >= lo && s[k] < hi) atomicAdd(&bins[s[k] - lo], 1u);
            if (d[k] >= lo && d[k] < hi && (unsigned)s[k] < (unsigned)n_nodes)
                atomicAdd(&bins[d[k] - lo], 0x10000u);
        }
    }
    for (; i < cnt; i += 256) {
        int ss = rp[(e0 + i) * stride];
        int dd = cp[(e0 + i) * stride];
        if (ss >= lo && ss < hi) atomicAdd(&bins[ss - lo], 1u);
        if (dd >= lo && dd < hi && (unsigned)ss < (unsigned)n_nodes)
            atomicAdd(&bins[dd - lo], 0x10000u);
    }
    __syncthreads();

    size_t base = (size_t)chunk * n_nodes + lo;
    for (int k = tid; k < nbins; k += 256) {
        u32 v = bins[k];
        row_slab[base + k] = (u16)(v & 0xFFFFu);
        col_slab[base + k] = (u16)(v >> 16);
    }
}

// ---------------- phase B1: y tile (fp32 compute, bf16 store) ----------------
static __device__ void ph_ytile(int t, int tid, float* __restrict__ smem,
                                const float* __restrict__ x, const float* __restrict__ M,
                                u16* __restrict__ y, int n_nodes) {
    __syncthreads();   // guard smem reuse across jobs
    float* Ms = smem;
    float (*xs)[IN_CH + 4] = (float(*)[IN_CH + 4])(smem + IN_CH * OUT_CH);
    int tx = tid & 15;
    int ty = tid >> 4;
    int row0 = t * 64;

    const float4* Mv = (const float4*)M;
    float4* Msv = (float4*)Ms;
#pragma unroll
    for (int k = 0; k < 8; ++k) Msv[tid + 256 * k] = Mv[tid + 256 * k];

    for (int f = tid; f < 64 * 32; f += 256) {
        int r = f >> 5, kq = f & 31;
        float4 v = make_float4(0.f, 0.f, 0.f, 0.f);
        if (row0 + r < n_nodes)
            v = *(const float4*)&x[(size_t)(row0 + r) * IN_CH + 4 * kq];
        *(float4*)&xs[r][4 * kq] = v;
    }
    __syncthreads();

    float4 acc[4];
#pragma unroll
    for (int j = 0; j < 4; ++j) acc[j] = make_float4(0.f, 0.f, 0.f, 0.f);

    for (int k = 0; k < IN_CH; k += 4) {
        float4 xr[4], mr[4];
#pragma unroll
        for (int j = 0; j < 4; ++j)
            xr[j] = *(const float4*)&xs[4 * ty + j][k];
#pragma unroll
        for (int kk = 0; kk < 4; ++kk)
            mr[kk] = *(const float4*)&Ms[(k + kk) * OUT_CH + 4 * tx];
#pragma unroll
        for (int j = 0; j < 4; ++j) {
            acc[j].x = fmaf(xr[j].x, mr[0].x, acc[j].x);
            acc[j].y = fmaf(xr[j].x, mr[0].y, acc[j].y);
            acc[j].z = fmaf(xr[j].x, mr[0].z, acc[j].z);
            acc[j].w = fmaf(xr[j].x, mr[0].w, acc[j].w);
            acc[j].x = fmaf(xr[j].y, mr[1].x, acc[j].x);
            acc[j].y = fmaf(xr[j].y, mr[1].y, acc[j].y);
            acc[j].z = fmaf(xr[j].y, mr[1].z, acc[j].z);
            acc[j].w = fmaf(xr[j].y, mr[1].w, acc[j].w);
            acc[j].x = fmaf(xr[j].z, mr[2].x, acc[j].x);
            acc[j].y = fmaf(xr[j].z, mr[2].y, acc[j].y);
            acc[j].z = fmaf(xr[j].z, mr[2].z, acc[j].z);
            acc[j].w = fmaf(xr[j].z, mr[2].w, acc[j].w);
            acc[j].x = fmaf(xr[j].w, mr[3].x, acc[j].x);
            acc[j].y = fmaf(xr[j].w, mr[3].y, acc[j].y);
            acc[j].z = fmaf(xr[j].w, mr[3].z, acc[j].z);
            acc[j].w = fmaf(xr[j].w, mr[3].w, acc[j].w);
        }
    }

#pragma unroll
    for (int j = 0; j < 4; ++j) {
        int r = row0 + 4 * ty + j;
        if (r < n_nodes) {
            ushort4 s4;
            s4.x = f2bf(acc[j].x);
            s4.y = f2bf(acc[j].y);
            s4.z = f2bf(acc[j].z);
            s4.w = f2bf(acc[j].w);
            *(ushort4*)&y[(size_t)r * OUT_CH + 4 * tx] = s4;
        }
    }
}

// ---------------- phase B2: choff + block-local scan ----------------
static __device__ void ph_choff(int jj, int tid, float* __restrict__ smem,
                                u16* __restrict__ row_slab, u16* __restrict__ col_slab,
                                int* __restrict__ deg_row, int* __restrict__ cnt_col,
                                int* __restrict__ cursor_part, int* __restrict__ bsums,
                                int n_nodes) {
    __syncthreads();   // guard smem reuse across jobs
    int* sm = (int*)smem;
    int n = jj * 256 + tid;
    int run = 0;
    if (n < n_nodes) {
        int sum = 0;
#pragma unroll 8
        for (int ch = 0; ch < NCHUNK; ++ch)
            sum += row_slab[(size_t)ch * n_nodes + n];
        deg_row[n] = sum;
#pragma unroll 8
        for (int ch = 0; ch < NCHUNK; ++ch) {
            int v = col_slab[(size_t)ch * n_nodes + n];
            col_slab[(size_t)ch * n_nodes + n] = (u16)run;
            run += v;
        }
        cnt_col[n] = run;
    }
    sm[tid] = run;
    __syncthreads();
    for (int d = 1; d < 256; d <<= 1) {
        int add = (tid >= d) ? sm[tid - d] : 0;
        __syncthreads();
        sm[tid] += add;
        __syncthreads();
    }
    if (n < n_nodes) cursor_part[n] = sm[tid] - run;
    if (tid == 255) bsums[jj] = sm[tid];
}

// in-block exclusive scan of bsums[0..nb) into bscan (nb <= 256)
static __device__ void block_bscan(const int* __restrict__ bsums, int nb,
                                   int* __restrict__ bscan) {
    int t = threadIdx.x;
    int v = (t < nb) ? bsums[t] : 0;
    bscan[t] = v;
    __syncthreads();
    for (int d = 1; d < 256; d <<= 1) {
        int add = (t >= d) ? bscan[t - d] : 0;
        __syncthreads();
        bscan[t] += add;
        __syncthreads();
    }
    bscan[t] -= v;
    __syncthreads();
}

// ---------------- phase C: place (counting sort, plain stores) ----------------
static __device__ void ph_place(int j, int tid, float* __restrict__ smem,
                                const int* __restrict__ ei,
                                const int* __restrict__ cursor_part,
                                const int* __restrict__ bsums,
                                const u16* __restrict__ col_slab,
                                int* __restrict__ csr_src,
                                int n_edges, int n_nodes, int nb) {
    int* rank = (int*)smem;
    int* bscan = (int*)smem + RBINS;
    block_bscan(bsums, nb, bscan);

    int chunk = j % NCHUNK;
    int range = j / NCHUNK;
    int range_size = (n_nodes + NRANGE - 1) / NRANGE;
    int lo = range * range_size;
    int hi = lo + range_size; if (hi > n_nodes) hi = n_nodes;
    if (hi <= lo) return;

    int stride = detect_stride_wave(ei);
    for (int i = tid; i < hi - lo; i += 256) rank[i] = 0;
    __syncthreads();

    size_t e0 = (size_t)chunk * n_edges / NCHUNK;
    size_t e1 = (size_t)(chunk + 1) * n_edges / NCHUNK;
    size_t cnt = e1 - e0;
    const int* rp = ei;
    const int* cp = ei + (size_t)n_edges * stride;
    size_t slab_base = (size_t)chunk * n_nodes;

    size_t i = tid;
    int s[8], d[8], cpart[8], coff[8];
    for (; i + 1792 < cnt; i += 2048) {
#pragma unroll
        for (int k = 0; k < 8; ++k) s[k] = rp[(e0 + i + 256 * k) * stride];
#pragma unroll
        for (int k = 0; k < 8; ++k) d[k] = cp[(e0 + i + 256 * k) * stride];
#pragma unroll
        for (int k = 0; k < 8; ++k) {
            int dc = (d[k] >= lo && d[k] < hi) ? d[k] : lo;
            cpart[k] = cursor_part[dc];
            coff[k]  = (int)col_slab[slab_base + dc];
        }
#pragma unroll
        for (int k = 0; k < 8; ++k) {
            if (d[k] >= lo && d[k] < hi && (unsigned)s[k] < (unsigned)n_nodes) {
                int r = atomicAdd(&rank[d[k] - lo], 1);
                csr_src[cpart[k] + bscan[d[k] >> 8] + coff[k] + r] = s[k];
            }
        }
    }
    for (; i < cnt; i += 256) {
        int ss = rp[(e0 + i) * stride];
        int dd = cp[(e0 + i) * stride];
        if (dd >= lo && dd < hi && (unsigned)ss < (unsigned)n_nodes) {
            int r = atomicAdd(&rank[dd - lo], 1);
            csr_src[cursor_part[dd] + bscan[dd >> 8] + (int)col_slab[slab_base + dd] + r] = ss;
        }
    }
}

// ---------------- phase D: gather-sum + finalize (16 dsts/block) ----------------
static __device__ void ph_agg(int g, int tid, const int* __restrict__ bscan,
                              const int* __restrict__ cursor_part,
                              const int* __restrict__ cnt_col,
                              const int* __restrict__ csr_src,
                              const int* __restrict__ deg_row,
                              const uint2* __restrict__ yv,
                              const float* __restrict__ c, const float* __restrict__ b2,
                              float* __restrict__ out, int n_nodes) {
    int sub = tid >> 4;       // 0..15: dst within block
    int ch  = tid & 15;       // 16 lanes x 8B = 128B row
    int d = g * 16 + sub;
    if (d >= n_nodes) return;

    int start = cursor_part[d] + bscan[d >> 8];
    int cnt = cnt_col[d];
    int end = start + cnt;
    int e1m = end - 1;
    float a0 = 0.f, a1 = 0.f, a2 = 0.f, a3 = 0.f;
    for (int j = start; j < end; j += 8) {
        int idx[8], srcs[8];
#pragma unroll
        for (int k = 0; k < 8; ++k) {
            int t = j + k;
            idx[k] = t > e1m ? e1m : t;
        }
#pragma unroll
        for (int k = 0; k < 8; ++k) srcs[k] = csr_src[idx[k]];
        uint2 u[8];
#pragma unroll
        for (int k = 0; k < 8; ++k) u[k] = yv[(size_t)srcs[k] * 16 + ch];
#pragma unroll
        for (int k = 1; k < 8; ++k)
            if (j + k >= end) { u[k].x = 0u; u[k].y = 0u; }
#pragma unroll
        for (int k = 0; k < 8; ++k) {
            a0 += bfu32_lo(u[k].x);
            a1 += bfu32_hi(u[k].x);
            a2 += bfu32_lo(u[k].y);
            a3 += bfu32_hi(u[k].y);
        }
    }
    int dr = deg_row[d];
    float di = (dr > 0) ? (1.0f / (float)dr) : 0.f;
    float fc = di * (float)cnt;
    float4 cv = ((const float4*)c)[ch];
    float4 bv = ((const float4*)b2)[ch];
    float4 o;
    o.x = di * a0 + fc * cv.x + bv.x;
    o.y = di * a1 + fc * cv.y + bv.y;
    o.z = di * a2 + fc * cv.z + bv.z;
    o.w = di * a3 + fc * cv.w + bv.w;
    ((float4*)(out + (size_t)d * OUT_CH))[ch] = o;
}

// ================= fused cooperative kernel =================
__global__ __launch_bounds__(256) void gnn_fused(const float* __restrict__ x,
                                                 const int* __restrict__ ei,
                                                 const float* __restrict__ W1,
                                                 const float* __restrict__ b1,
                                                 const float* __restrict__ W2,
                                                 const float* __restrict__ b2,
                                                 float* __restrict__ out,
                                                 float* __restrict__ M,
                                                 float* __restrict__ c,
                                                 int* __restrict__ deg_row,
                                                 int* __restrict__ cnt_col,
                                                 int* __restrict__ cursor_part,
                                                 int* __restrict__ bsums,
                                                 u16* __restrict__ row_slab,
                                                 u16* __restrict__ col_slab,
                                                 int* __restrict__ csr_src,
                                                 u16* __restrict__ y,
                                                 int n_nodes, int n_edges) {
    __shared__ float smem[SMEM_FLOATS];
    cg::grid_group grid = cg::this_grid();
    int b = blockIdx.x, tid = threadIdx.x;
    int y_blocks = (n_nodes + 63) >> 6;
    int nb = (n_nodes + 255) >> 8;

    // phase A
    if (b < MC_BLOCKS) ph_Mc(b, tid, W1, b1, W2, M, c);
    else if (b < MC_BLOCKS + NCHUNK * NRANGE)
        ph_hist(b - MC_BLOCKS, tid, smem, ei, row_slab, col_slab, n_edges, n_nodes);
    grid.sync();

    // phase B
    int njobs = y_blocks + nb;
    for (int j = b; j < njobs; j += gridDim.x) {
        if (j < y_blocks) ph_ytile(j, tid, smem, x, M, y, n_nodes);
        else ph_choff(j - y_blocks, tid, smem, row_slab, col_slab, deg_row,
                      cnt_col, cursor_part, bsums, n_nodes);
    }
    grid.sync();

    // phase C
    if (b < NCHUNK * NRANGE)
        ph_place(b, tid, smem, ei, cursor_part, bsums, col_slab, csr_src,
                 n_edges, n_nodes, nb);
    grid.sync();

    // phase D
    int* bscan = (int*)smem;
    block_bscan(bsums, nb, bscan);
    int ngroups = (n_nodes + 15) >> 4;
    for (int g = b; g < ngroups; g += gridDim.x)
        ph_agg(g, tid, bscan, cursor_part, cnt_col, csr_src, deg_row,
               (const uint2*)y, c, b2, out, n_nodes);
}

// ================= fallback kernels (if cooperative launch rejected) =================
__global__ __launch_bounds__(256) void k_prep(const float* __restrict__ W1,
                                              const float* __restrict__ b1,
                                              const float* __restrict__ W2,
                                              const int* __restrict__ ei,
                                              float* __restrict__ M, float* __restrict__ c,
                                              u16* __restrict__ row_slab,
                                              u16* __restrict__ col_slab,
                                              int n_edges, int n_nodes) {
    __shared__ float smem[SMEM_FLOATS];
    int b = blockIdx.x;
    if (b < MC_BLOCKS) ph_Mc(b, threadIdx.x, W1, b1, W2, M, c);
    else ph_hist(b - MC_BLOCKS, threadIdx.x, smem, ei, row_slab, col_slab,
                 n_edges, n_nodes);
}

__global__ __launch_bounds__(256) void k_ych(const float* __restrict__ x,
                                             const float* __restrict__ M,
                                             u16* __restrict__ y,
                                             u16* __restrict__ row_slab,
                                             u16* __restrict__ col_slab,
                                             int* __restrict__ deg_row,
                                             int* __restrict__ cnt_col,
                                             int* __restrict__ cursor_part,
                                             int* __restrict__ bsums,
                                             int n_nodes, int y_blocks) {
    __shared__ float smem[SMEM_FLOATS];
    int j = blockIdx.x;
    if (j < y_blocks) ph_ytile(j, threadIdx.x, smem, x, M, y, n_nodes);
    else ph_choff(j - y_blocks, threadIdx.x, smem, row_slab, col_slab, deg_row,
                  cnt_col, cursor_part, bsums, n_nodes);
}

__global__ __launch_bounds__(256) void k_place(const int* __restrict__ ei,
                                               const int* __restrict__ cursor_part,
                                               const int* __restrict__ bsums,
                                               const u16* __restrict__ col_slab,
                                               int* __restrict__ csr_src,
                                               int n_edges, int n_nodes, int nb) {
    __shared__ float smem[SMEM_FLOATS];
    ph_place(blockIdx.x, threadIdx.x, smem, ei, cursor_part, bsums, col_slab,
             csr_src, n_edges, n_nodes, nb);
}

__global__ __launch_bounds__(256) void k_agg(const int* __restrict__ cursor_part,
                                             const int* __restrict__ bsums,
                                             const int* __restrict__ cnt_col,
                                             const int* __restrict__ csr_src,
                                             const int* __restrict__ deg_row,
                                             const uint2* __restrict__ yv,
                                             const float* __restrict__ c,
                                             const float* __restrict__ b2,
                                             float* __restrict__ out,
                                             int n_nodes, int nb) {
    __shared__ int bscan[256];
    block_bscan(bsums, nb, bscan);
    ph_agg(blockIdx.x, threadIdx.x, bscan, cursor_part, cnt_col, csr_src,
           deg_row, yv, c, b2, out, n_nodes);
}

extern "C" void kernel_launch(void* const* d_in, const int* in_sizes, int n_in,
                              void* d_out, int out_size, void* d_ws, size_t ws_size,
                              hipStream_t stream) {
    const float* x  = (const float*)d_in[0];
    const int*   ei = (const int*)d_in[1];
    const float* W1 = (const float*)d_in[2];
    const float* b1 = (const float*)d_in[3];
    const float* W2 = (const float*)d_in[4];
    const float* b2 = (const float*)d_in[5];
    float* out = (float*)d_out;

    int n_nodes = in_sizes[0] / IN_CH;     // 50000
    int n_edges = in_sizes[1] / 2;         // 800000

    const size_t slab_bytes = (((size_t)NCHUNK * n_nodes * 2) + 127) & ~(size_t)127;
    const size_t csr_bytes  = ((size_t)n_edges * 4 + 127) & ~(size_t)127;

    char* ws = (char*)d_ws;
    float* M        = (float*)(ws);                    // 32768
    float* c        = (float*)(ws + 32768);            // 256
    int*   deg_row  = (int*)  (ws + 33152);            // 200064
    int*   cnt_col  = (int*)  (ws + 233216);           // 200064
    int*   cursor   = (int*)  (ws + 433280);           // 200064 (cursor_part)
    int*   bsums    = (int*)  (ws + 633344);           // 4096
    u16*   row_slab = (u16*)  (ws + 637440);           // 11.2 MB
    u16*   col_slab = (u16*)  (ws + 637440 + slab_bytes);
    int*   csr_src  = (int*)  (ws + 637440 + 2 * slab_bytes);
    u16*   y        = (u16*)  (ws + 637440 + 2 * slab_bytes + csr_bytes);

    int y_blocks = (n_nodes + 63) / 64;                // 782
    int nb = (n_nodes + 255) / 256;                    // 196

    void* args[] = {
        (void*)&x, (void*)&ei, (void*)&W1, (void*)&b1, (void*)&W2, (void*)&b2,
        (void*)&out, (void*)&M, (void*)&c, (void*)&deg_row, (void*)&cnt_col,
        (void*)&cursor, (void*)&bsums, (void*)&row_slab, (void*)&col_slab,
        (void*)&csr_src, (void*)&y, (void*)&n_nodes, (void*)&n_edges
    };
    hipError_t err = hipLaunchCooperativeKernel((void*)gnn_fused, dim3(GRID),
                                                dim3(256), args, 0, stream);
    if (err != hipSuccess) {
        // fallback: 4 sequential dispatches (identical math)
        k_prep<<<MC_BLOCKS + NCHUNK * NRANGE, 256, 0, stream>>>(
            W1, b1, W2, ei, M, c, row_slab, col_slab, n_edges, n_nodes);
        k_ych<<<y_blocks + nb, 256, 0, stream>>>(
            x, M, y, row_slab, col_slab, deg_row, cnt_col, cursor, bsums,
            n_nodes, y_blocks);
        k_place<<<NCHUNK * NRANGE, 256, 0, stream>>>(
            ei, cursor, bsums, col_slab, csr_src, n_edges, n_nodes, nb);
        k_agg<<<(n_nodes + 15) / 16, 256, 0, stream>>>(
            cursor, bsums, cnt_col, csr_src, deg_row, (const uint2*)y, c, b2,
            out, n_nodes, nb);
    }
}

// Round 11
// 165.871 us; speedup vs baseline: 2.2417x; 2.2417x over previous
//
#include <hip/hip_runtime.h>
#include <hip/hip_bf16.h>

// SimpleGNN on MI355X — fp32 in/out, edge_index int32/int64 auto-detect.
// out[d] = di[d]*(S[d] @ M) + di[d]*cnt_col[d]*c + b2
//   M = W1^T W2^T [128x64], c = b1 @ W2^T [64]
//   S[d] = sum_{e: col_e=d} x[row_e],  di[d] = 1/deg_row[d] (0 if deg 0)
// Zero global atomics; y bf16; 4 dispatches.
// R10 lesson (cooperative experiment): edge phases are latency-bound and
// scale with resident waves — fused @8 waves/CU took 285 us vs 162 total.
// R11: every phase gets >=3-4 blocks/CU (small LDS + >=1024-block grids).

#define IN_CH   128
#define OUT_CH  64
#define NCHUNK  128
#define LGCHUNK 7
#define NRANGE  8
#define RBINS   6272    // ceil(50176/8); 25 KB bins
#define MC_BLOCKS 33    // ceil((128*64+64)/256)
#define YROWS   32

typedef unsigned short u16;
typedef unsigned int u32;

static __device__ inline float bfu32_lo(u32 u) { return __uint_as_float(u << 16); }
static __device__ inline float bfu32_hi(u32 u) { return __uint_as_float(u & 0xffff0000u); }
static __device__ inline u16 f2bf(float f) {
    __hip_bfloat16 h = __float2bfloat16(f);
    return *reinterpret_cast<u16*>(&h);
}

// wave-parallel stride detect: int64 edge_index => odd int32 words all 0
static __device__ inline int detect_stride_wave(const int* __restrict__ ei) {
    int lane = threadIdx.x & 63;
    int idx = (lane < 32) ? (2 * lane + 1) : 1;
    int v = ei[idx];
    unsigned long long m = __ballot((v != 0) && (lane < 32));
    return (m == 0ull) ? 2 : 1;
}

// ================= K1: [M_c | hist] =================
__global__ __launch_bounds__(256) void mk_prep(const float* __restrict__ W1,
                                               const float* __restrict__ b1,
                                               const float* __restrict__ W2,
                                               const int* __restrict__ ei,
                                               float* __restrict__ M,
                                               float* __restrict__ c,
                                               u16* __restrict__ row_slab,
                                               u16* __restrict__ col_slab,
                                               int n_edges, int n_nodes) {
    __shared__ u32 bins[RBINS];
    int b = blockIdx.x;
    int tid = threadIdx.x;
    if (b < MC_BLOCKS) {
        int t = b * 256 + tid;
        if (t < IN_CH * OUT_CH) {
            int o = t & (OUT_CH - 1);
            int i = t >> 6;
            float acc = 0.f;
            for (int h = 0; h < 128; ++h)
                acc += W1[h * 128 + i] * W2[o * 128 + h];
            M[i * OUT_CH + o] = acc;
        } else if (t < IN_CH * OUT_CH + OUT_CH) {
            int o = t - IN_CH * OUT_CH;
            float acc = 0.f;
            for (int h = 0; h < 128; ++h)
                acc += b1[h] * W2[o * 128 + h];
            c[o] = acc;
        }
        return;
    }
    // ---- hist: row counts in lo16, col counts in hi16 ----
    int hb = b - MC_BLOCKS;
    int chunk = hb & (NCHUNK - 1);
    int range = hb >> LGCHUNK;

    int range_size = (n_nodes + NRANGE - 1) / NRANGE;
    int lo = range * range_size;
    int hi = lo + range_size; if (hi > n_nodes) hi = n_nodes;
    int nbins = hi - lo;
    if (nbins <= 0) return;

    int stride = detect_stride_wave(ei);
    for (int i = tid; i < nbins; i += 256) bins[i] = 0u;
    __syncthreads();

    size_t e0 = (size_t)chunk * n_edges / NCHUNK;
    size_t e1 = (size_t)(chunk + 1) * n_edges / NCHUNK;
    size_t cnt = e1 - e0;
    const int* rp = ei;
    const int* cp = ei + (size_t)n_edges * stride;

    size_t i = tid;
    int s[8], d[8];
    for (; i + 1792 < cnt; i += 2048) {
#pragma unroll
        for (int k = 0; k < 8; ++k) s[k] = rp[(e0 + i + 256 * k) * stride];
#pragma unroll
        for (int k = 0; k < 8; ++k) d[k] = cp[(e0 + i + 256 * k) * stride];
#pragma unroll
        for (int k = 0; k < 8; ++k) {
            if (s[k] >= lo && s[k] < hi) atomicAdd(&bins[s[k] - lo], 1u);
            if (d[k] >= lo && d[k] < hi && (unsigned)s[k] < (unsigned)n_nodes)
                atomicAdd(&bins[d[k] - lo], 0x10000u);
        }
    }
    for (; i < cnt; i += 256) {
        int ss = rp[(e0 + i) * stride];
        int dd = cp[(e0 + i) * stride];
        if (ss >= lo && ss < hi) atomicAdd(&bins[ss - lo], 1u);
        if (dd >= lo && dd < hi && (unsigned)ss < (unsigned)n_nodes)
            atomicAdd(&bins[dd - lo], 0x10000u);
    }
    __syncthreads();

    size_t base = (size_t)chunk * n_nodes + lo;
    for (int k = tid; k < nbins; k += 256) {
        u32 v = bins[k];
        row_slab[base + k] = (u16)(v & 0xFFFFu);
        col_slab[base + k] = (u16)(v >> 16);
    }
}

// ================= K2: [y (32-row tiles) | choff_scan] =================
__global__ __launch_bounds__(256) void mk_y_choff(const float* __restrict__ x,
                                                  const float* __restrict__ M,
                                                  u16* __restrict__ y,
                                                  u16* __restrict__ row_slab,
                                                  u16* __restrict__ col_slab,
                                                  int* __restrict__ deg_row,
                                                  int* __restrict__ cnt_col,
                                                  int* __restrict__ cursor_part,
                                                  int* __restrict__ bsums,
                                                  int n_nodes, int y_blocks) {
    __shared__ float smem[IN_CH * OUT_CH + YROWS * (IN_CH + 4)];  // 49.6 KB
    int b = blockIdx.x;
    int tid = threadIdx.x;

    if (b < y_blocks) {
        float* Ms = smem;
        float (*xs)[IN_CH + 4] = (float(*)[IN_CH + 4])(smem + IN_CH * OUT_CH);
        int tx = tid & 15;     // col group: 4*tx
        int ty = tid >> 4;     // 0..15; rows ty and ty+16
        int row0 = b * YROWS;

        const float4* Mv = (const float4*)M;
        float4* Msv = (float4*)Ms;
#pragma unroll
        for (int k = 0; k < 8; ++k) Msv[tid + 256 * k] = Mv[tid + 256 * k];

        for (int f = tid; f < YROWS * 32; f += 256) {
            int r = f >> 5, kq = f & 31;
            float4 v = make_float4(0.f, 0.f, 0.f, 0.f);
            if (row0 + r < n_nodes)
                v = *(const float4*)&x[(size_t)(row0 + r) * IN_CH + 4 * kq];
            *(float4*)&xs[r][4 * kq] = v;
        }
        __syncthreads();

        float4 acc0 = make_float4(0.f, 0.f, 0.f, 0.f);
        float4 acc1 = make_float4(0.f, 0.f, 0.f, 0.f);

        for (int k = 0; k < IN_CH; k += 4) {
            float4 xr0 = *(const float4*)&xs[ty][k];
            float4 xr1 = *(const float4*)&xs[ty + 16][k];
            float4 m0 = *(const float4*)&Ms[(k + 0) * OUT_CH + 4 * tx];
            float4 m1 = *(const float4*)&Ms[(k + 1) * OUT_CH + 4 * tx];
            float4 m2 = *(const float4*)&Ms[(k + 2) * OUT_CH + 4 * tx];
            float4 m3 = *(const float4*)&Ms[(k + 3) * OUT_CH + 4 * tx];
            acc0.x = fmaf(xr0.x, m0.x, acc0.x); acc0.y = fmaf(xr0.x, m0.y, acc0.y);
            acc0.z = fmaf(xr0.x, m0.z, acc0.z); acc0.w = fmaf(xr0.x, m0.w, acc0.w);
            acc0.x = fmaf(xr0.y, m1.x, acc0.x); acc0.y = fmaf(xr0.y, m1.y, acc0.y);
            acc0.z = fmaf(xr0.y, m1.z, acc0.z); acc0.w = fmaf(xr0.y, m1.w, acc0.w);
            acc0.x = fmaf(xr0.z, m2.x, acc0.x); acc0.y = fmaf(xr0.z, m2.y, acc0.y);
            acc0.z = fmaf(xr0.z, m2.z, acc0.z); acc0.w = fmaf(xr0.z, m2.w, acc0.w);
            acc0.x = fmaf(xr0.w, m3.x, acc0.x); acc0.y = fmaf(xr0.w, m3.y, acc0.y);
            acc0.z = fmaf(xr0.w, m3.z, acc0.z); acc0.w = fmaf(xr0.w, m3.w, acc0.w);
            acc1.x = fmaf(xr1.x, m0.x, acc1.x); acc1.y = fmaf(xr1.x, m0.y, acc1.y);
            acc1.z = fmaf(xr1.x, m0.z, acc1.z); acc1.w = fmaf(xr1.x, m0.w, acc1.w);
            acc1.x = fmaf(xr1.y, m1.x, acc1.x); acc1.y = fmaf(xr1.y, m1.y, acc1.y);
            acc1.z = fmaf(xr1.y, m1.z, acc1.z); acc1.w = fmaf(xr1.y, m1.w, acc1.w);
            acc1.x = fmaf(xr1.z, m2.x, acc1.x); acc1.y = fmaf(xr1.z, m2.y, acc1.y);
            acc1.z = fmaf(xr1.z, m2.z, acc1.z); acc1.w = fmaf(xr1.z, m2.w, acc1.w);
            acc1.x = fmaf(xr1.w, m3.x, acc1.x); acc1.y = fmaf(xr1.w, m3.y, acc1.y);
            acc1.z = fmaf(xr1.w, m3.z, acc1.z); acc1.w = fmaf(xr1.w, m3.w, acc1.w);
        }

        int r0 = row0 + ty;
        int r1 = row0 + ty + 16;
        if (r0 < n_nodes) {
            ushort4 s4;
            s4.x = f2bf(acc0.x); s4.y = f2bf(acc0.y);
            s4.z = f2bf(acc0.z); s4.w = f2bf(acc0.w);
            *(ushort4*)&y[(size_t)r0 * OUT_CH + 4 * tx] = s4;
        }
        if (r1 < n_nodes) {
            ushort4 s4;
            s4.x = f2bf(acc1.x); s4.y = f2bf(acc1.y);
            s4.z = f2bf(acc1.z); s4.w = f2bf(acc1.w);
            *(ushort4*)&y[(size_t)r1 * OUT_CH + 4 * tx] = s4;
        }
        return;
    }

    // ---- choff_scan ----
    int* sm = (int*)smem;
    int t = tid;
    int n = (b - y_blocks) * 256 + t;
    int run = 0;
    if (n < n_nodes) {
        int sum = 0;
#pragma unroll 8
        for (int ch = 0; ch < NCHUNK; ++ch)
            sum += row_slab[(size_t)ch * n_nodes + n];
        deg_row[n] = sum;
#pragma unroll 8
        for (int ch = 0; ch < NCHUNK; ++ch) {
            int v = col_slab[(size_t)ch * n_nodes + n];
            col_slab[(size_t)ch * n_nodes + n] = (u16)run;
            run += v;
        }
        cnt_col[n] = run;
    }
    sm[t] = run;
    __syncthreads();
    for (int d = 1; d < 256; d <<= 1) {
        int add = (t >= d) ? sm[t - d] : 0;
        __syncthreads();
        sm[t] += add;
        __syncthreads();
    }
    if (n < n_nodes) cursor_part[n] = sm[t] - run;
    if (t == 255) bsums[b - y_blocks] = sm[t];
}

// in-block exclusive scan of bsums[0..nb) into bscan (nb <= 256)
static __device__ void block_bscan(const int* __restrict__ bsums, int nb,
                                   int* __restrict__ bscan) {
    int t = threadIdx.x;
    int v = (t < nb) ? bsums[t] : 0;
    bscan[t] = v;
    __syncthreads();
    for (int d = 1; d < 256; d <<= 1) {
        int add = (t >= d) ? bscan[t - d] : 0;
        __syncthreads();
        bscan[t] += add;
        __syncthreads();
    }
    bscan[t] -= v;
    __syncthreads();
}

// ================= K3: place =================
__global__ __launch_bounds__(256) void mk_place(const int* __restrict__ ei,
                                                const int* __restrict__ cursor_part,
                                                const int* __restrict__ bsums,
                                                const u16* __restrict__ col_slab,
                                                int* __restrict__ csr_src,
                                                int n_edges, int n_nodes, int nb) {
    __shared__ int rank[RBINS];
    __shared__ int bscan[256];
    block_bscan(bsums, nb, bscan);

    int b = blockIdx.x;
    int chunk = b & (NCHUNK - 1);
    int range = b >> LGCHUNK;

    int range_size = (n_nodes + NRANGE - 1) / NRANGE;
    int lo = range * range_size;
    int hi = lo + range_size; if (hi > n_nodes) hi = n_nodes;
    if (hi <= lo) return;

    int stride = detect_stride_wave(ei);
    for (int i = threadIdx.x; i < hi - lo; i += 256) rank[i] = 0;
    __syncthreads();

    size_t e0 = (size_t)chunk * n_edges / NCHUNK;
    size_t e1 = (size_t)(chunk + 1) * n_edges / NCHUNK;
    size_t cnt = e1 - e0;
    const int* rp = ei;
    const int* cp = ei + (size_t)n_edges * stride;
    size_t slab_base = (size_t)chunk * n_nodes;

    size_t i = threadIdx.x;
    int s[8], d[8], cpart[8], coff[8];
    for (; i + 1792 < cnt; i += 2048) {
#pragma unroll
        for (int k = 0; k < 8; ++k) s[k] = rp[(e0 + i + 256 * k) * stride];
#pragma unroll
        for (int k = 0; k < 8; ++k) d[k] = cp[(e0 + i + 256 * k) * stride];
#pragma unroll
        for (int k = 0; k < 8; ++k) {
            int dc = (d[k] >= lo && d[k] < hi) ? d[k] : lo;
            cpart[k] = cursor_part[dc];
            coff[k]  = (int)col_slab[slab_base + dc];
        }
#pragma unroll
        for (int k = 0; k < 8; ++k) {
            if (d[k] >= lo && d[k] < hi && (unsigned)s[k] < (unsigned)n_nodes) {
                int r = atomicAdd(&rank[d[k] - lo], 1);
                csr_src[cpart[k] + bscan[d[k] >> 8] + coff[k] + r] = s[k];
            }
        }
    }
    for (; i < cnt; i += 256) {
        int ss = rp[(e0 + i) * stride];
        int dd = cp[(e0 + i) * stride];
        if (dd >= lo && dd < hi && (unsigned)ss < (unsigned)n_nodes) {
            int r = atomicAdd(&rank[dd - lo], 1);
            csr_src[cursor_part[dd] + bscan[dd >> 8] + (int)col_slab[slab_base + dd] + r] = ss;
        }
    }
}

// ================= K4: agg_final (4 dsts/wave, uint2 gather) =================
__global__ __launch_bounds__(256) void mk_agg_final(const int* __restrict__ cursor_part,
                                                    const int* __restrict__ bsums,
                                                    const int* __restrict__ cnt_col,
                                                    const int* __restrict__ csr_src,
                                                    const int* __restrict__ deg_row,
                                                    const uint2* __restrict__ yv,
                                                    const float* __restrict__ c,
                                                    const float* __restrict__ b2,
                                                    float* __restrict__ out,
                                                    int n_nodes, int nb) {
    __shared__ int bscan[256];
    block_bscan(bsums, nb, bscan);

    int wave = threadIdx.x >> 6;
    int lane = threadIdx.x & 63;
    int dsub = lane >> 4;
    int ch   = lane & 15;
    int d = blockIdx.x * 16 + wave * 4 + dsub;
    if (d >= n_nodes) return;

    int start = cursor_part[d] + bscan[d >> 8];
    int cnt = cnt_col[d];
    int end = start + cnt;
    int e1m = end - 1;
    float a0 = 0.f, a1 = 0.f, a2 = 0.f, a3 = 0.f;
    for (int j = start; j < end; j += 8) {
        int idx[8], srcs[8];
#pragma unroll
        for (int k = 0; k < 8; ++k) {
            int t = j + k;
            idx[k] = t > e1m ? e1m : t;
        }
#pragma unroll
        for (int k = 0; k < 8; ++k) srcs[k] = csr_src[idx[k]];
        uint2 u[8];
#pragma unroll
        for (int k = 0; k < 8; ++k) u[k] = yv[(size_t)srcs[k] * 16 + ch];
#pragma unroll
        for (int k = 1; k < 8; ++k)
            if (j + k >= end) { u[k].x = 0u; u[k].y = 0u; }
#pragma unroll
        for (int k = 0; k < 8; ++k) {
            a0 += bfu32_lo(u[k].x);
            a1 += bfu32_hi(u[k].x);
            a2 += bfu32_lo(u[k].y);
            a3 += bfu32_hi(u[k].y);
        }
    }
    int dr = deg_row[d];
    float di = (dr > 0) ? (1.0f / (float)dr) : 0.f;
    float fc = di * (float)cnt;
    float4 cv = ((const float4*)c)[ch];
    float4 bv = ((const float4*)b2)[ch];
    float4 o;
    o.x = di * a0 + fc * cv.x + bv.x;
    o.y = di * a1 + fc * cv.y + bv.y;
    o.z = di * a2 + fc * cv.z + bv.z;
    o.w = di * a3 + fc * cv.w + bv.w;
    ((float4*)(out + (size_t)d * OUT_CH))[ch] = o;
}

extern "C" void kernel_launch(void* const* d_in, const int* in_sizes, int n_in,
                              void* d_out, int out_size, void* d_ws, size_t ws_size,
                              hipStream_t stream) {
    const float* x  = (const float*)d_in[0];
    const int*   ei = (const int*)d_in[1];
    const float* W1 = (const float*)d_in[2];
    const float* b1 = (const float*)d_in[3];
    const float* W2 = (const float*)d_in[4];
    const float* b2 = (const float*)d_in[5];
    float* out = (float*)d_out;

    const int n_nodes = in_sizes[0] / IN_CH;     // 50000
    const int n_edges = in_sizes[1] / 2;         // 800000

    const size_t slab_bytes = (((size_t)NCHUNK * n_nodes * 2) + 127) & ~(size_t)127;
    const size_t csr_bytes  = ((size_t)n_edges * 4 + 127) & ~(size_t)127;

    char* ws = (char*)d_ws;
    float* M        = (float*)(ws);                    // 32768
    float* c        = (float*)(ws + 32768);            // 256
    int*   deg_row  = (int*)  (ws + 33152);            // 200064
    int*   cnt_col  = (int*)  (ws + 233216);           // 200064
    int*   cursor   = (int*)  (ws + 433280);           // 200064 (cursor_part)
    int*   bsums    = (int*)  (ws + 633344);           // 4096
    u16*   row_slab = (u16*)  (ws + 637440);           // 12.8 MB
    u16*   col_slab = (u16*)  (ws + 637440 + slab_bytes);
    int*   csr_src  = (int*)  (ws + 637440 + 2 * slab_bytes);
    u16*   y        = (u16*)  (ws + 637440 + 2 * slab_bytes + csr_bytes);

    const int y_blocks = (n_nodes + YROWS - 1) / YROWS;  // 1563
    const int nb = (n_nodes + 255) / 256;                // 196 (<=256 required)

    mk_prep<<<MC_BLOCKS + NCHUNK * NRANGE, 256, 0, stream>>>(
        W1, b1, W2, ei, M, c, row_slab, col_slab, n_edges, n_nodes);

    mk_y_choff<<<y_blocks + nb, 256, 0, stream>>>(
        x, M, y, row_slab, col_slab, deg_row, cnt_col, cursor, bsums,
        n_nodes, y_blocks);

    mk_place<<<NCHUNK * NRANGE, 256, 0, stream>>>(
        ei, cursor, bsums, col_slab, csr_src, n_edges, n_nodes, nb);

    mk_agg_final<<<(n_nodes + 15) / 16, 256, 0, stream>>>(
        cursor, bsums, cnt_col, csr_src, deg_row, (const uint2*)y, c, b2, out,
        n_nodes, nb);
}

// Round 12
// 154.888 us; speedup vs baseline: 2.4006x; 1.0709x over previous
//
#include <hip/hip_runtime.h>
#include <hip/hip_bf16.h>

// SimpleGNN on MI355X — fp32 in/out, edge_index int32/int64 auto-detect.
// out[d] = di[d]*(S[d] @ M) + di[d]*cnt_col[d]*c + b2
//   M = W1^T W2^T [128x64], c = b1 @ W2^T [64]
//   S[d] = sum_{e: col_e=d} x[row_e],  di[d] = 1/deg_row[d] (0 if deg 0)
// Zero global atomics; y bf16; 4 dispatches re-balanced (R12):
//   K1 [M_c | hist]   K2 [choff]   K3 [place ∥ y]   K4 [agg_final]
// R11 lesson: phases are latency-bound and insensitive to occupancy/work
// tweaks; only concurrency pairing moves the total. Pair place with y.

#define IN_CH   128
#define OUT_CH  64
#define NCHUNK  64
#define NRANGE  8
#define RBINS   6272    // ceil(50176/8); 25 KB bins
#define MC_BLOCKS 33
#define MC_PAD  40      // pad to multiple of 8 so hist ranges stay XCD-aligned
#define YROWS   32
#define PLACE_BLOCKS (NCHUNK * NRANGE)   // 512
// union smem: y needs 32KB Ms + 32*(132)*4 = 48.5 KB; place needs 25.5 KB
#define SMEM_FLOATS (IN_CH * OUT_CH + YROWS * (IN_CH + 4))   // 12416 fl = 49664 B

typedef unsigned short u16;
typedef unsigned int u32;

static __device__ inline float bfu32_lo(u32 u) { return __uint_as_float(u << 16); }
static __device__ inline float bfu32_hi(u32 u) { return __uint_as_float(u & 0xffff0000u); }
static __device__ inline u16 f2bf(float f) {
    __hip_bfloat16 h = __float2bfloat16(f);
    return *reinterpret_cast<u16*>(&h);
}

// wave-parallel stride detect: int64 edge_index => odd int32 words all 0
static __device__ inline int detect_stride_wave(const int* __restrict__ ei) {
    int lane = threadIdx.x & 63;
    int idx = (lane < 32) ? (2 * lane + 1) : 1;
    int v = ei[idx];
    unsigned long long m = __ballot((v != 0) && (lane < 32));
    return (m == 0ull) ? 2 : 1;
}

// ================= K1: [M_c | hist] =================
// hist block mapping: range = hb & 7 (XCD-aligned: all blocks of range r land
// on XCD r, keeping that range's slab region in one L2), chunk = hb >> 3.
__global__ __launch_bounds__(256) void mk_prep(const float* __restrict__ W1,
                                               const float* __restrict__ b1,
                                               const float* __restrict__ W2,
                                               const int* __restrict__ ei,
                                               float* __restrict__ M,
                                               float* __restrict__ c,
                                               u16* __restrict__ row_slab,
                                               u16* __restrict__ col_slab,
                                               int n_edges, int n_nodes) {
    __shared__ u32 bins[RBINS];
    int b = blockIdx.x;
    int tid = threadIdx.x;
    if (b < MC_PAD) {
        int t = b * 256 + tid;
        if (t < IN_CH * OUT_CH) {
            int o = t & (OUT_CH - 1);
            int i = t >> 6;
            float acc = 0.f;
            for (int h = 0; h < 128; ++h)
                acc += W1[h * 128 + i] * W2[o * 128 + h];
            M[i * OUT_CH + o] = acc;
        } else if (t < IN_CH * OUT_CH + OUT_CH) {
            int o = t - IN_CH * OUT_CH;
            float acc = 0.f;
            for (int h = 0; h < 128; ++h)
                acc += b1[h] * W2[o * 128 + h];
            c[o] = acc;
        }
        return;
    }
    // ---- hist: row counts in lo16, col counts in hi16 ----
    int hb = b - MC_PAD;
    int range = hb & (NRANGE - 1);
    int chunk = hb >> 3;

    int range_size = (n_nodes + NRANGE - 1) / NRANGE;
    int lo = range * range_size;
    int hi = lo + range_size; if (hi > n_nodes) hi = n_nodes;
    int nbins = hi - lo;
    if (nbins <= 0) return;

    int stride = detect_stride_wave(ei);
    for (int i = tid; i < nbins; i += 256) bins[i] = 0u;
    __syncthreads();

    size_t e0 = (size_t)chunk * n_edges / NCHUNK;
    size_t e1 = (size_t)(chunk + 1) * n_edges / NCHUNK;
    size_t cnt = e1 - e0;
    const int* rp = ei;
    const int* cp = ei + (size_t)n_edges * stride;

    size_t i = tid;
    int s[8], d[8];
    for (; i + 1792 < cnt; i += 2048) {
#pragma unroll
        for (int k = 0; k < 8; ++k) s[k] = rp[(e0 + i + 256 * k) * stride];
#pragma unroll
        for (int k = 0; k < 8; ++k) d[k] = cp[(e0 + i + 256 * k) * stride];
#pragma unroll
        for (int k = 0; k < 8; ++k) {
            if (s[k] >= lo && s[k] < hi) atomicAdd(&bins[s[k] - lo], 1u);
            if (d[k] >= lo && d[k] < hi && (unsigned)s[k] < (unsigned)n_nodes)
                atomicAdd(&bins[d[k] - lo], 0x10000u);
        }
    }
    for (; i < cnt; i += 256) {
        int ss = rp[(e0 + i) * stride];
        int dd = cp[(e0 + i) * stride];
        if (ss >= lo && ss < hi) atomicAdd(&bins[ss - lo], 1u);
        if (dd >= lo && dd < hi && (unsigned)ss < (unsigned)n_nodes)
            atomicAdd(&bins[dd - lo], 0x10000u);
    }
    __syncthreads();

    size_t base = (size_t)chunk * n_nodes + lo;
    for (int k = tid; k < nbins; k += 256) {
        u32 v = bins[k];
        row_slab[base + k] = (u16)(v & 0xFFFFu);
        col_slab[base + k] = (u16)(v >> 16);
    }
}

// ================= K2: choff + block-local scan (small, fast) =================
__global__ __launch_bounds__(256) void mk_choff(u16* __restrict__ row_slab,
                                                u16* __restrict__ col_slab,
                                                int* __restrict__ deg_row,
                                                int* __restrict__ cnt_col,
                                                int* __restrict__ cursor_part,
                                                int* __restrict__ bsums,
                                                int n_nodes) {
    __shared__ int sm[256];
    int t = threadIdx.x;
    int n = blockIdx.x * 256 + t;
    int run = 0;
    if (n < n_nodes) {
        int sum = 0;
#pragma unroll 8
        for (int ch = 0; ch < NCHUNK; ++ch)
            sum += row_slab[(size_t)ch * n_nodes + n];
        deg_row[n] = sum;
#pragma unroll 8
        for (int ch = 0; ch < NCHUNK; ++ch) {
            int v = col_slab[(size_t)ch * n_nodes + n];
            col_slab[(size_t)ch * n_nodes + n] = (u16)run;
            run += v;
        }
        cnt_col[n] = run;
    }
    sm[t] = run;
    __syncthreads();
    for (int d = 1; d < 256; d <<= 1) {
        int add = (t >= d) ? sm[t - d] : 0;
        __syncthreads();
        sm[t] += add;
        __syncthreads();
    }
    if (n < n_nodes) cursor_part[n] = sm[t] - run;
    if (t == 255) bsums[blockIdx.x] = sm[t];
}

// in-block exclusive scan of bsums[0..nb) into bscan (nb <= 256)
static __device__ void block_bscan(const int* __restrict__ bsums, int nb,
                                   int* __restrict__ bscan) {
    int t = threadIdx.x;
    int v = (t < nb) ? bsums[t] : 0;
    bscan[t] = v;
    __syncthreads();
    for (int d = 1; d < 256; d <<= 1) {
        int add = (t >= d) ? bscan[t - d] : 0;
        __syncthreads();
        bscan[t] += add;
        __syncthreads();
    }
    bscan[t] -= v;
    __syncthreads();
}

// ================= K3: [place ∥ y] =================
// place blocks first (ids 0..511, XCD-aligned ranges), y blocks after.
__global__ __launch_bounds__(256) void mk_place_y(const int* __restrict__ ei,
                                                  const int* __restrict__ cursor_part,
                                                  const int* __restrict__ bsums,
                                                  const u16* __restrict__ col_slab,
                                                  int* __restrict__ csr_src,
                                                  const float* __restrict__ x,
                                                  const float* __restrict__ M,
                                                  u16* __restrict__ y,
                                                  int n_edges, int n_nodes, int nb) {
    __shared__ float smem[SMEM_FLOATS];
    int b = blockIdx.x;
    int tid = threadIdx.x;

    if (b < PLACE_BLOCKS) {
        // ---- place ----
        int* rank = (int*)smem;
        int* bscan = (int*)smem + RBINS;
        block_bscan(bsums, nb, bscan);

        int range = b & (NRANGE - 1);
        int chunk = b >> 3;
        int range_size = (n_nodes + NRANGE - 1) / NRANGE;
        int lo = range * range_size;
        int hi = lo + range_size; if (hi > n_nodes) hi = n_nodes;
        if (hi <= lo) return;

        int stride = detect_stride_wave(ei);
        for (int i = tid; i < hi - lo; i += 256) rank[i] = 0;
        __syncthreads();

        size_t e0 = (size_t)chunk * n_edges / NCHUNK;
        size_t e1 = (size_t)(chunk + 1) * n_edges / NCHUNK;
        size_t cnt = e1 - e0;
        const int* rp = ei;
        const int* cp = ei + (size_t)n_edges * stride;
        size_t slab_base = (size_t)chunk * n_nodes;

        size_t i = tid;
        int s[8], d[8], cpart[8], coff[8];
        for (; i + 1792 < cnt; i += 2048) {
#pragma unroll
            for (int k = 0; k < 8; ++k) s[k] = rp[(e0 + i + 256 * k) * stride];
#pragma unroll
            for (int k = 0; k < 8; ++k) d[k] = cp[(e0 + i + 256 * k) * stride];
#pragma unroll
            for (int k = 0; k < 8; ++k) {
                int dc = (d[k] >= lo && d[k] < hi) ? d[k] : lo;
                cpart[k] = cursor_part[dc];
                coff[k]  = (int)col_slab[slab_base + dc];
            }
#pragma unroll
            for (int k = 0; k < 8; ++k) {
                if (d[k] >= lo && d[k] < hi && (unsigned)s[k] < (unsigned)n_nodes) {
                    int r = atomicAdd(&rank[d[k] - lo], 1);
                    csr_src[cpart[k] + bscan[d[k] >> 8] + coff[k] + r] = s[k];
                }
            }
        }
        for (; i < cnt; i += 256) {
            int ss = rp[(e0 + i) * stride];
            int dd = cp[(e0 + i) * stride];
            if (dd >= lo && dd < hi && (unsigned)ss < (unsigned)n_nodes) {
                int r = atomicAdd(&rank[dd - lo], 1);
                csr_src[cursor_part[dd] + bscan[dd >> 8] + (int)col_slab[slab_base + dd] + r] = ss;
            }
        }
        return;
    }

    // ---- y tile (32 rows) ----
    int t = b - PLACE_BLOCKS;
    float* Ms = smem;
    float (*xs)[IN_CH + 4] = (float(*)[IN_CH + 4])(smem + IN_CH * OUT_CH);
    int tx = tid & 15;
    int ty = tid >> 4;
    int row0 = t * YROWS;
    if (row0 >= n_nodes) return;

    const float4* Mv = (const float4*)M;
    float4* Msv = (float4*)Ms;
#pragma unroll
    for (int k = 0; k < 8; ++k) Msv[tid + 256 * k] = Mv[tid + 256 * k];

    for (int f = tid; f < YROWS * 32; f += 256) {
        int r = f >> 5, kq = f & 31;
        float4 v = make_float4(0.f, 0.f, 0.f, 0.f);
        if (row0 + r < n_nodes)
            v = *(const float4*)&x[(size_t)(row0 + r) * IN_CH + 4 * kq];
        *(float4*)&xs[r][4 * kq] = v;
    }
    __syncthreads();

    float4 acc0 = make_float4(0.f, 0.f, 0.f, 0.f);
    float4 acc1 = make_float4(0.f, 0.f, 0.f, 0.f);

    for (int k = 0; k < IN_CH; k += 4) {
        float4 xr0 = *(const float4*)&xs[ty][k];
        float4 xr1 = *(const float4*)&xs[ty + 16][k];
        float4 m0 = *(const float4*)&Ms[(k + 0) * OUT_CH + 4 * tx];
        float4 m1 = *(const float4*)&Ms[(k + 1) * OUT_CH + 4 * tx];
        float4 m2 = *(const float4*)&Ms[(k + 2) * OUT_CH + 4 * tx];
        float4 m3 = *(const float4*)&Ms[(k + 3) * OUT_CH + 4 * tx];
        acc0.x = fmaf(xr0.x, m0.x, acc0.x); acc0.y = fmaf(xr0.x, m0.y, acc0.y);
        acc0.z = fmaf(xr0.x, m0.z, acc0.z); acc0.w = fmaf(xr0.x, m0.w, acc0.w);
        acc0.x = fmaf(xr0.y, m1.x, acc0.x); acc0.y = fmaf(xr0.y, m1.y, acc0.y);
        acc0.z = fmaf(xr0.y, m1.z, acc0.z); acc0.w = fmaf(xr0.y, m1.w, acc0.w);
        acc0.x = fmaf(xr0.z, m2.x, acc0.x); acc0.y = fmaf(xr0.z, m2.y, acc0.y);
        acc0.z = fmaf(xr0.z, m2.z, acc0.z); acc0.w = fmaf(xr0.z, m2.w, acc0.w);
        acc0.x = fmaf(xr0.w, m3.x, acc0.x); acc0.y = fmaf(xr0.w, m3.y, acc0.y);
        acc0.z = fmaf(xr0.w, m3.z, acc0.z); acc0.w = fmaf(xr0.w, m3.w, acc0.w);
        acc1.x = fmaf(xr1.x, m0.x, acc1.x); acc1.y = fmaf(xr1.x, m0.y, acc1.y);
        acc1.z = fmaf(xr1.x, m0.z, acc1.z); acc1.w = fmaf(xr1.x, m0.w, acc1.w);
        acc1.x = fmaf(xr1.y, m1.x, acc1.x); acc1.y = fmaf(xr1.y, m1.y, acc1.y);
        acc1.z = fmaf(xr1.y, m1.z, acc1.z); acc1.w = fmaf(xr1.y, m1.w, acc1.w);
        acc1.x = fmaf(xr1.z, m2.x, acc1.x); acc1.y = fmaf(xr1.z, m2.y, acc1.y);
        acc1.z = fmaf(xr1.z, m2.z, acc1.z); acc1.w = fmaf(xr1.z, m2.w, acc1.w);
        acc1.x = fmaf(xr1.w, m3.x, acc1.x); acc1.y = fmaf(xr1.w, m3.y, acc1.y);
        acc1.z = fmaf(xr1.w, m3.z, acc1.z); acc1.w = fmaf(xr1.w, m3.w, acc1.w);
    }

    int r0 = row0 + ty;
    int r1 = row0 + ty + 16;
    if (r0 < n_nodes) {
        ushort4 s4;
        s4.x = f2bf(acc0.x); s4.y = f2bf(acc0.y);
        s4.z = f2bf(acc0.z); s4.w = f2bf(acc0.w);
        *(ushort4*)&y[(size_t)r0 * OUT_CH + 4 * tx] = s4;
    }
    if (r1 < n_nodes) {
        ushort4 s4;
        s4.x = f2bf(acc1.x); s4.y = f2bf(acc1.y);
        s4.z = f2bf(acc1.z); s4.w = f2bf(acc1.w);
        *(ushort4*)&y[(size_t)r1 * OUT_CH + 4 * tx] = s4;
    }
}

// ================= K4: agg_final (4 dsts/wave, uint2 gather) =================
__global__ __launch_bounds__(256) void mk_agg_final(const int* __restrict__ cursor_part,
                                                    const int* __restrict__ bsums,
                                                    const int* __restrict__ cnt_col,
                                                    const int* __restrict__ csr_src,
                                                    const int* __restrict__ deg_row,
                                                    const uint2* __restrict__ yv,
                                                    const float* __restrict__ c,
                                                    const float* __restrict__ b2,
                                                    float* __restrict__ out,
                                                    int n_nodes, int nb) {
    __shared__ int bscan[256];
    block_bscan(bsums, nb, bscan);

    int wave = threadIdx.x >> 6;
    int lane = threadIdx.x & 63;
    int dsub = lane >> 4;
    int ch   = lane & 15;
    int d = blockIdx.x * 16 + wave * 4 + dsub;
    if (d >= n_nodes) return;

    int start = cursor_part[d] + bscan[d >> 8];
    int cnt = cnt_col[d];
    int end = start + cnt;
    int e1m = end - 1;
    float a0 = 0.f, a1 = 0.f, a2 = 0.f, a3 = 0.f;
    for (int j = start; j < end; j += 8) {
        int idx[8], srcs[8];
#pragma unroll
        for (int k = 0; k < 8; ++k) {
            int t = j + k;
            idx[k] = t > e1m ? e1m : t;
        }
#pragma unroll
        for (int k = 0; k < 8; ++k) srcs[k] = csr_src[idx[k]];
        uint2 u[8];
#pragma unroll
        for (int k = 0; k < 8; ++k) u[k] = yv[(size_t)srcs[k] * 16 + ch];
#pragma unroll
        for (int k = 1; k < 8; ++k)
            if (j + k >= end) { u[k].x = 0u; u[k].y = 0u; }
#pragma unroll
        for (int k = 0; k < 8; ++k) {
            a0 += bfu32_lo(u[k].x);
            a1 += bfu32_hi(u[k].x);
            a2 += bfu32_lo(u[k].y);
            a3 += bfu32_hi(u[k].y);
        }
    }
    int dr = deg_row[d];
    float di = (dr > 0) ? (1.0f / (float)dr) : 0.f;
    float fc = di * (float)cnt;
    float4 cv = ((const float4*)c)[ch];
    float4 bv = ((const float4*)b2)[ch];
    float4 o;
    o.x = di * a0 + fc * cv.x + bv.x;
    o.y = di * a1 + fc * cv.y + bv.y;
    o.z = di * a2 + fc * cv.z + bv.z;
    o.w = di * a3 + fc * cv.w + bv.w;
    ((float4*)(out + (size_t)d * OUT_CH))[ch] = o;
}

extern "C" void kernel_launch(void* const* d_in, const int* in_sizes, int n_in,
                              void* d_out, int out_size, void* d_ws, size_t ws_size,
                              hipStream_t stream) {
    const float* x  = (const float*)d_in[0];
    const int*   ei = (const int*)d_in[1];
    const float* W1 = (const float*)d_in[2];
    const float* b1 = (const float*)d_in[3];
    const float* W2 = (const float*)d_in[4];
    const float* b2 = (const float*)d_in[5];
    float* out = (float*)d_out;

    const int n_nodes = in_sizes[0] / IN_CH;     // 50000
    const int n_edges = in_sizes[1] / 2;         // 800000

    const size_t slab_bytes = (((size_t)NCHUNK * n_nodes * 2) + 127) & ~(size_t)127;
    const size_t csr_bytes  = ((size_t)n_edges * 4 + 127) & ~(size_t)127;

    char* ws = (char*)d_ws;
    float* M        = (float*)(ws);                    // 32768
    float* c        = (float*)(ws + 32768);            // 256
    int*   deg_row  = (int*)  (ws + 33152);            // 200064
    int*   cnt_col  = (int*)  (ws + 233216);           // 200064
    int*   cursor   = (int*)  (ws + 433280);           // 200064 (cursor_part)
    int*   bsums    = (int*)  (ws + 633344);           // 4096
    u16*   row_slab = (u16*)  (ws + 637440);           // 6.4 MB
    u16*   col_slab = (u16*)  (ws + 637440 + slab_bytes);
    int*   csr_src  = (int*)  (ws + 637440 + 2 * slab_bytes);
    u16*   y        = (u16*)  (ws + 637440 + 2 * slab_bytes + csr_bytes);

    const int y_blocks = (n_nodes + YROWS - 1) / YROWS;  // 1563
    const int nb = (n_nodes + 255) / 256;                // 196 (<=256 required)

    mk_prep<<<MC_PAD + NCHUNK * NRANGE, 256, 0, stream>>>(
        W1, b1, W2, ei, M, c, row_slab, col_slab, n_edges, n_nodes);

    mk_choff<<<nb, 256, 0, stream>>>(row_slab, col_slab, deg_row, cnt_col,
                                     cursor, bsums, n_nodes);

    mk_place_y<<<PLACE_BLOCKS + y_blocks, 256, 0, stream>>>(
        ei, cursor, bsums, col_slab, csr_src, x, M, y, n_edges, n_nodes, nb);

    mk_agg_final<<<(n_nodes + 15) / 16, 256, 0, stream>>>(
        cursor, bsums, cnt_col, csr_src, deg_row, (const uint2*)y, c, b2, out,
        n_nodes, nb);
}